// Round 5
// baseline (400.230 us; speedup 1.0000x reference)
//
#include <hip/hip_runtime.h>

#define HW 36864      // 192*192
#define IMGS 128      // B*C

static __device__ __forceinline__ int imax(int a, int b) { return a > b ? a : b; }
static __device__ __forceinline__ int imin(int a, int b) { return a < b ? a : b; }

__device__ __constant__ float LIFT_C[6] = {
  -0.5f, 0.25f,                                            // bior53
  -1.586134342f, -0.05298011854f, 0.8829110762f, 0.4435068522f  // bior97
};

// raw (unnormalized) FIR lowpass filters concatenated: db4(8) db6(12) sym6(12) coif5(30)
__device__ constexpr float FIRC[62] = {
  -0.0105974017850021f, 0.0328830116668852f, 0.0308413818355607f, -0.1870348117188811f,
  -0.0279837694169839f, 0.6308807679295904f, 0.7148465705529155f, 0.2303778133088964f,
  0.00107730108499558f, -0.00477725751101065f, -0.0005538422009938f, 0.03158203931748603f,
  0.02752286553030533f, -0.0975016055873225f, -0.12976686756709563f, 0.22626469396544f,
  0.3152503517092432f, -0.7511339080210959f, 0.4946238903984534f, 0.1115407433501095f,
  -0.007800708325034148f, 0.001767711864242804f, 0.04472490177066578f, -0.02106029251230056f,
  -0.0726375227866f, 0.3379294217282401f, 0.787641141030194f, 0.4910559419267466f,
  -0.048311742585632f, -0.1179901111484105f, 0.00349071208421747f, 0.01540410932702737f,
  -3.459977283621256e-05f, -7.098330313814114e-05f, 0.0004662169601128863f, 0.001117518770890601f,
  -0.002574517688750223f, -0.00900797613666158f, 0.015880544863615904f, 0.03455502757306163f,
  -0.08230192710688598f, -0.07179982161931202f, 0.42848347637761874f, 0.7937772226256206f,
  0.4051769024096169f, -0.06112339000267287f, -0.06577191128185562f, 0.023452696141836267f,
  0.007782596427325418f, -0.003793512864491014f, -0.0002606761356811993f, 0.000107502882505652f,
  1.10319778524429e-05f, -5.520763127949e-06f, -1.0682196848076e-06f, 5.236425333584e-07f,
  1.125098976034e-07f, -5.417490769329e-08f, -8.8631e-09f, 4.2921e-09f, 6.7e-10f, -3.2e-10f,
};

// ---------------- gate: 1x1 conv -> relu -> 1x1 conv -> softmax -> renorm ----------------
__global__ __launch_bounds__(256) void k_gate(
    const float* __restrict__ x, const float* __restrict__ w1, const float* __restrict__ b1,
    const float* __restrict__ w2, const float* __restrict__ b2, float* __restrict__ gate)
{
  __shared__ float w1s[256], b1s[8], w2s[48], b2s[6];
  int tid = threadIdx.x;
  w1s[tid] = w1[tid];
  if (tid < 8)  b1s[tid] = b1[tid];
  if (tid < 48) w2s[tid] = w2[tid];
  if (tid < 6)  b2s[tid] = b2[tid];
  __syncthreads();
  int px = blockIdx.x * 256 + tid;        // exactly 4*HW threads
  int b = px / HW, p = px - b * HW;
  const float* xb = x + (size_t)b * 32 * HW + p;
  float xv[32];
#pragma unroll
  for (int c = 0; c < 32; ++c) xv[c] = xb[(size_t)c * HW];
  float hb[8];
#pragma unroll
  for (int j = 0; j < 8; ++j) {
    float s = b1s[j];
#pragma unroll
    for (int c = 0; c < 32; ++c) s += w1s[j * 32 + c] * xv[c];
    hb[j] = fmaxf(s, 0.f);
  }
  float e[6], mx = -1e30f;
#pragma unroll
  for (int k = 0; k < 6; ++k) {
    float s = b2s[k];
#pragma unroll
    for (int j = 0; j < 8; ++j) s += w2s[k * 8 + j] * hb[j];
    e[k] = s; mx = fmaxf(mx, s);
  }
  float se = 0.f;
#pragma unroll
  for (int k = 0; k < 6; ++k) { e[k] = expf(e[k] - mx); se += e[k]; }
  float inv = 1.f / se, s2 = 0.f;
#pragma unroll
  for (int k = 0; k < 6; ++k) { e[k] *= inv; s2 += e[k]; }
  float inv2 = 1.f / (s2 + 1e-12f);
  float* gp = gate + (size_t)b * 6 * HW + p;
#pragma unroll
  for (int k = 0; k < 6; ++k) gp[(size_t)k * HW] = e[k] * inv2;
}

// ---------------- fused 2D lifting: whole image in LDS, in-place ----------------
// grid (128 imgs, 2 cands), 1024 threads, 148224 B dynamic LDS
__global__ __launch_bounds__(1024) void k_lift(
    const float* __restrict__ x, float* __restrict__ halfp,
    const float* __restrict__ s53A, const float* __restrict__ s53D,
    const float* __restrict__ s97A, const float* __restrict__ s97D)
{
  extern __shared__ float xs[];   // [192][193]
  const int tid = threadIdx.x;
  const int img = blockIdx.x;
  const int cand = blockIdx.y;    // 0: bior53, 1: bior97
  const float* xi = x + (size_t)img * HW;
  for (int i = tid; i < HW; i += 1024) {
    int r = i / 192, c = i - r * 192;
    xs[r * 193 + c] = xi[i];
  }
  __syncthreads();
  const int base = cand ? 2 : 0, ns = cand ? 4 : 2;
  // W lifting (in place, columns interleaved even/odd)
  for (int s = 0; s < ns; ++s) {
    const float cf = LIFT_C[base + s] * 0.5f;
    for (int i = tid; i < 192 * 96; i += 1024) {
      int j = i % 96, r = i / 96;
      int jm = (j == 0) ? 1 : j - 1, jp = (j == 95) ? 94 : j + 1;
      float* row = xs + r * 193;
      if ((s & 1) == 0) row[2 * j + 1] += cf * (row[2 * jm] + row[2 * jp]);
      else              row[2 * j]     += cf * (row[2 * jm + 1] + row[2 * jp + 1]);
    }
    __syncthreads();
  }
  // H lifting (in place, rows interleaved even/odd)
  for (int s = 0; s < ns; ++s) {
    const float cf = LIFT_C[base + s] * 0.5f;
    for (int i = tid; i < 192 * 96; i += 1024) {
      int c = i % 192, j = i / 192;
      int jm = (j == 0) ? 1 : j - 1, jp = (j == 95) ? 94 : j + 1;
      if ((s & 1) == 0) xs[(2 * j + 1) * 193 + c] += cf * (xs[(2 * jm) * 193 + c] + xs[(2 * jp) * 193 + c]);
      else              xs[(2 * j) * 193 + c]     += cf * (xs[(2 * jm + 1) * 193 + c] + xs[(2 * jp + 1) * 193 + c]);
    }
    __syncthreads();
  }
  const float sA = cand ? s97A[0] : s53A[0];
  const float sD = cand ? s97D[0] : s53D[0];
  const float sc[4] = { sA * sA, sA * sD, sA * sD, sD * sD };   // hf applied later in k3 store
  for (int i = tid; i < 4 * 9216; i += 1024) {
    int s = i / 9216, p = i - s * 9216;
    int u = p / 96, v = p - u * 96;
    int ro = (s & 1) ? (2 * u + 1) : (2 * u);
    int co = (s & 2) ? (2 * v + 1) : (2 * v);
    halfp[((size_t)(cand * 4 + s) * IMGS + img) * 9216 + p] = sc[s] * xs[ro * 193 + co];
  }
}

// ---------------- fused FIR candidate (one candidate, 32x32 tile) ----------------
// Resize blend simplified: q0(w) = w - d (d=1 for w<=95, 2 else), e==0 everywhere,
// dup only at w==0 (use pos idx 1 twice) and w==191 (v1=v0). t = d - (2w+1)/192.
// Tap-chunked (CHW/CHH taps per chunk): caps the live LDS window at CH+8 floats.
// coif5's win[38] was the VGPR allocation peak (132 VGPR -> 3 blocks/CU instead of 4).
// Accumulation order (ascending j for fixed position) is unchanged -> numerics identical.
template<int L, int PA, int OFF, int CHW, int CHH>
__device__ __forceinline__ void fir_cand(
    const float* xt, float* lbs, float* hbs,
    int row, int g, int c, int g2,
    int xoff, float t0w, int leftW, int rightW,
    int rb0, float t0h, int topH, int botH,
    const float* __restrict__ gp, float (&acc)[4][4])
{
  float ss = 0.f;
#pragma unroll
  for (int j = 0; j < L; ++j) ss += FIRC[OFF + j] * FIRC[OFF + j];
  const float invn = 1.f / (sqrtf(ss) + 1e-12f);
  const float invn2 = invn * invn;

  // ---- W pass ----
  {
    const int xb = row * 65 + (xoff - PA);
    float Lp[9], Hp[9];
#pragma unroll
    for (int p = 0; p < 9; ++p) { Lp[p] = 0.f; Hp[p] = 0.f; }
#pragma unroll
    for (int c0 = 0; c0 < L; c0 += CHW) {
      const int CL = (c0 + CHW <= L) ? CHW : (L - c0);
      float win[CHW + 8];
#pragma unroll
      for (int m = 0; m < CL + 8; ++m) win[m] = xt[xb + c0 + m];
#pragma unroll
      for (int p = 0; p < 9; ++p) {
        float a = Lp[p], d = Hp[p];
#pragma unroll
        for (int j = 0; j < CL; ++j) {
          const float v = win[p + j];
          a += FIRC[OFF + c0 + j] * v;
          d += ((((c0 + j) & 1) ? -1.f : 1.f) * FIRC[OFF + L - 1 - (c0 + j)]) * v;
        }
        Lp[p] = a; Hp[p] = d;
      }
    }
    const int ob = row * 33 + g * 8;
#pragma unroll
    for (int k = 0; k < 8; ++k) {
      float v0l = Lp[k], v1l = Lp[k + 1];
      float v0h = Hp[k], v1h = Hp[k + 1];
      if (k == 0 && leftW)  { v0l = Lp[1]; v1l = Lp[1]; v0h = Hp[1]; v1h = Hp[1]; }
      if (k == 7 && rightW) { v1l = v0l; v1h = v0h; }
      const float t = t0w - (float)k * (1.f / 96.f);
      lbs[ob + k] = fmaf(t, v1l - v0l, v0l);
      hbs[ob + k] = fmaf(t, v1h - v0h, v0h);
    }
  }
  __syncthreads();
  // ---- H pass ----
  {
    const int rb = rb0 - PA;
    float LLp[5], LHp[5], HLp[5], HHp[5];
#pragma unroll
    for (int p = 0; p < 5; ++p) { LLp[p] = 0.f; LHp[p] = 0.f; }
#pragma unroll
    for (int c0 = 0; c0 < L; c0 += CHH) {
      const int CL = (c0 + CHH <= L) ? CHH : (L - c0);
      float win[CHH + 4];
#pragma unroll
      for (int m = 0; m < CL + 4; ++m) win[m] = lbs[(rb + c0 + m) * 33 + c];
#pragma unroll
      for (int p = 0; p < 5; ++p) {
        float a = LLp[p], d = LHp[p];
#pragma unroll
        for (int j = 0; j < CL; ++j) {
          const float v = win[p + j];
          a += FIRC[OFF + c0 + j] * v;
          d += ((((c0 + j) & 1) ? -1.f : 1.f) * FIRC[OFF + L - 1 - (c0 + j)]) * v;
        }
        LLp[p] = a; LHp[p] = d;
      }
    }
#pragma unroll
    for (int p = 0; p < 5; ++p) { HLp[p] = 0.f; HHp[p] = 0.f; }
#pragma unroll
    for (int c0 = 0; c0 < L; c0 += CHH) {
      const int CL = (c0 + CHH <= L) ? CHH : (L - c0);
      float win[CHH + 4];
#pragma unroll
      for (int m = 0; m < CL + 4; ++m) win[m] = hbs[(rb + c0 + m) * 33 + c];
#pragma unroll
      for (int p = 0; p < 5; ++p) {
        float a = HLp[p], d = HHp[p];
#pragma unroll
        for (int j = 0; j < CL; ++j) {
          const float v = win[p + j];
          a += FIRC[OFF + c0 + j] * v;
          d += ((((c0 + j) & 1) ? -1.f : 1.f) * FIRC[OFF + L - 1 - (c0 + j)]) * v;
        }
        HLp[p] = a; HHp[p] = d;
      }
    }
#pragma unroll
    for (int k = 0; k < 4; ++k) {
      const float t = t0h - (float)k * (1.f / 96.f);
      float v0a = LLp[k], v1a = LLp[k + 1];
      float v0b = LHp[k], v1b = LHp[k + 1];
      float v0c = HLp[k], v1c = HLp[k + 1];
      float v0d = HHp[k], v1d = HHp[k + 1];
      if (k == 0 && topH) { v0a = v1a = LLp[1]; v0b = v1b = LHp[1]; v0c = v1c = HLp[1]; v0d = v1d = HHp[1]; }
      if (k == 3 && botH) { v1a = v0a; v1b = v0b; v1c = v0c; v1d = v0d; }
      const float gv = gp[k * 192] * invn2;     // gate load, just-in-time
      acc[k][0] += gv * fmaf(t, v1a - v0a, v0a);
      acc[k][1] += gv * fmaf(t, v1b - v0b, v0b);
      acc[k][2] += gv * fmaf(t, v1c - v0c, v0c);
      acc[k][3] += gv * fmaf(t, v1d - v0d, v0d);
    }
  }
  __syncthreads();
}

// ---------------- fused per-tile kernel: 4 FIR cands + lifting gather + gate ----------------
__global__ __launch_bounds__(256) void k3_fused(
    const float* __restrict__ x, const float* __restrict__ gate,
    const float* __restrict__ halfp, const float* __restrict__ hfp, float* __restrict__ sf)
{
  __shared__ float xt[64 * 65];
  __shared__ float wb[2 * 64 * 33];
  float* lbs = wb;
  float* hbs = wb + 64 * 33;
  const int tid = threadIdx.x;
  const int tile = blockIdx.x;
  const int ty = tile / 6, tx = tile - ty * 6;
  const int img = blockIdx.y;
  const int b = img >> 5;
  const int h0 = ty * 32, w0 = tx * 32;

  const float* xi = x + (size_t)img * HW;
  for (int v = tid; v < 64 * 64; v += 256) {
    int l = v >> 6, m = v & 63;
    int ar = h0 - 16 + l; ar = ar < 0 ? -ar : (ar > 191 ? 382 - ar : ar);
    int ac = w0 - 16 + m; ac = ac < 0 ? -ac : (ac > 191 ? 382 - ac : ac);
    xt[l * 65 + m] = xi[ar * 192 + ac];
  }

  // roles
  const int row = tid >> 2, g = tid & 3;          // W pass
  const int c = tid & 31, g2 = tid >> 5;          // H pass / output
  // W blend params (shared by all 4 FIR cands)
  const int wf = w0 + g * 8;
  const int dW = (wf >= 96) ? 2 : 1;
  const float t0w = (float)dW - (float)(2 * wf + 1) * (1.f / 192.f);
  const int xoff = wf - dW + 16 - w0;
  const int leftW = (wf == 0), rightW = (wf == 184);
  // H blend params
  const int hfirst = h0 + g2 * 4;
  const int dH = (hfirst >= 96) ? 2 : 1;
  const float t0h = (float)dH - (float)(2 * hfirst + 1) * (1.f / 192.f);
  const int rb0 = g2 * 4 - dH + 16;
  const int topH = (hfirst == 0), botH = (hfirst == 188);

  const int wpx = w0 + c;
  // per-pixel gate base (candidate kk's pointer = gbase + kk*HW)
  const float* gbase = gate + (size_t)(b * 6) * HW + (size_t)hfirst * 192 + wpx;
  float acc[4][4];
#pragma unroll
  for (int k = 0; k < 4; ++k)
#pragma unroll
    for (int s = 0; s < 4; ++s) acc[k][s] = 0.f;
  __syncthreads();

  fir_cand<8, 2, 0, 8, 8>(xt, lbs, hbs, row, g, c, g2, xoff, t0w, leftW, rightW, rb0, t0h, topH, botH, gbase, acc);
  fir_cand<12, 4, 8, 12, 12>(xt, lbs, hbs, row, g, c, g2, xoff, t0w, leftW, rightW, rb0, t0h, topH, botH, gbase + HW, acc);
  fir_cand<12, 4, 20, 12, 12>(xt, lbs, hbs, row, g, c, g2, xoff, t0w, leftW, rightW, rb0, t0h, topH, botH, gbase + 2 * HW, acc);
  fir_cand<30, 13, 32, 15, 15>(xt, lbs, hbs, row, g, c, g2, xoff, t0w, leftW, rightW, rb0, t0h, topH, botH, gbase + 3 * HW, acc);

  // ---- lifting gather: stage 18x18 half-res windows of 8 planes as [pos][4] ----
  float* ls4 = wb;   // reuse (2592 <= 4224 floats)
  const int hu0 = (h0 >> 1) - 1, wv0 = (w0 >> 1) - 1;
  for (int v = tid; v < 2592; v += 256) {
    int lv = v % 18; int r1 = v / 18;
    int lu = r1 % 18; int ps = r1 / 18;      // ps = lc*4+s
    int lc = ps >> 2;
    int gu = imin(imax(hu0 + lu, 0), 95);
    int gv = imin(imax(wv0 + lv, 0), 95);
    ls4[(lc * 324 + lu * 18 + lv) * 4 + (ps & 3)] =
        halfp[((size_t)ps * IMGS + img) * 9216 + (size_t)gu * 96 + gv];
  }
  __syncthreads();

  const int v0c = (wpx >> 1) + (wpx & 1) - 1;
  const float tv = (wpx & 1) ? 0.25f : 0.75f;
  const int lv0 = imax(v0c, 0) - wv0;
  const int lv1 = imin(v0c + 1, 95) - wv0;
#pragma unroll
  for (int k = 0; k < 4; ++k) {
    const int h = hfirst + k;
    const int u0 = (h >> 1) + (h & 1) - 1;
    const float tu = (h & 1) ? 0.25f : 0.75f;
    const int lu0 = imax(u0, 0) - hu0;
    const int lu1 = imin(u0 + 1, 95) - hu0;
    const float w00 = (1.f - tu) * (1.f - tv), w01 = (1.f - tu) * tv;
    const float w10 = tu * (1.f - tv), w11 = tu * tv;
#pragma unroll
    for (int lc = 0; lc < 2; ++lc) {
      const int b00 = (lc * 324 + lu0 * 18 + lv0) * 4;
      const int b01 = (lc * 324 + lu0 * 18 + lv1) * 4;
      const int b10 = (lc * 324 + lu1 * 18 + lv0) * 4;
      const int b11 = (lc * 324 + lu1 * 18 + lv1) * 4;
      const float gv = gbase[(size_t)(4 + lc) * HW + k * 192];   // lifting gate, just-in-time
#pragma unroll
      for (int s = 0; s < 4; ++s) {
        float val = w00 * ls4[b00 + s] + w01 * ls4[b01 + s] +
                    w10 * ls4[b10 + s] + w11 * ls4[b11 + s];
        acc[k][s] += gv * val;
      }
    }
  }
  // ---- store Sf (hf folded in here, once, for all candidates) ----
  const float hfv = hfp[0];
#pragma unroll
  for (int k = 0; k < 4; ++k) {
    const int h = hfirst + k;
    size_t basep = (size_t)img * 4 * HW + (size_t)h * 192 + wpx;
    sf[basep]            = acc[k][0];
    sf[basep + HW]       = hfv * acc[k][1];
    sf[basep + 2 * HW]   = hfv * acc[k][2];
    sf[basep + 3 * HW]   = hfv * acc[k][3];
  }
}

// ---------------- final 1x1 projection 128 -> 32 ----------------
// 2304 blocks x 256 thr; 4 waves/block share one 64-px slab (L1 reuse);
// weights via wave-uniform (readfirstlane) scalar loads.
__global__ __launch_bounds__(256) void k_proj(
    const float* __restrict__ sf, const float* __restrict__ pw,
    const float* __restrict__ pb, float* __restrict__ out)
{
  const int tid = threadIdx.x;
  const int lane = tid & 63;
  const int og = __builtin_amdgcn_readfirstlane(tid >> 6);   // 0..3, wave-uniform scalar
  const int b = blockIdx.x / 576;                             // 576 blocks per image
  const int p = blockIdx.x * 64 - b * HW + lane;
  const float* sfb = sf + (size_t)(b * 128) * HW + p;
  const float* pwb = pw + og * 8 * 128;                       // scalar base
  float acc[8];
#pragma unroll
  for (int oo = 0; oo < 8; ++oo) acc[oo] = 0.f;
#pragma unroll 4
  for (int ch = 0; ch < 128; ++ch) {
    const float v = sfb[(size_t)ch * HW];
#pragma unroll
    for (int oo = 0; oo < 8; ++oo) acc[oo] = fmaf(pwb[oo * 128 + ch], v, acc[oo]);
  }
#pragma unroll
  for (int oo = 0; oo < 8; ++oo) {
    out[(size_t)(b * 32 + og * 8 + oo) * HW + p] = acc[oo] + pb[og * 8 + oo];
  }
}

extern "C" void kernel_launch(void* const* d_in, const int* in_sizes, int n_in,
                              void* d_out, int out_size, void* d_ws, size_t ws_size,
                              hipStream_t stream) {
  (void)in_sizes; (void)n_in; (void)out_size; (void)ws_size;
  const float* x    = (const float*)d_in[0];
  const float* gw1  = (const float*)d_in[1];
  const float* gb1  = (const float*)d_in[2];
  const float* gw2  = (const float*)d_in[3];
  const float* gb2  = (const float*)d_in[4];
  const float* s53A = (const float*)d_in[5];
  const float* s53D = (const float*)d_in[6];
  const float* s97A = (const float*)d_in[7];
  const float* s97D = (const float*)d_in[8];
  const float* hfp  = (const float*)d_in[9];
  const float* pw   = (const float*)d_in[10];
  const float* pb   = (const float*)d_in[11];
  float* out = (float*)d_out;
  float* ws = (float*)d_ws;

  float* gate = ws;                         // 884736 floats
  float* half = ws + 884736;                // 9437184 floats (2 cand x 4 sub x 128 x 96x96)
  float* sf   = ws + 884736 + 9437184;      // 18874368 floats (128 x 4 x 192x192)

  hipLaunchKernelGGL(k_gate, dim3(576), dim3(256), 0, stream, x, gw1, gb1, gw2, gb2, gate);
  hipLaunchKernelGGL(k_lift, dim3(128, 2), dim3(1024), 192 * 193 * 4, stream,
                     x, half, s53A, s53D, s97A, s97D);
  hipLaunchKernelGGL(k3_fused, dim3(36, 128), dim3(256), 0, stream, x, gate, half, hfp, sf);
  hipLaunchKernelGGL(k_proj, dim3(2304), dim3(256), 0, stream, sf, pw, pb, out);
}

// Round 6
// 377.141 us; speedup vs baseline: 1.0612x; 1.0612x over previous
//
#include <hip/hip_runtime.h>
#include <hip/hip_fp16.h>

#define HW 36864      // 192*192
#define IMGS 128      // B*C

static __device__ __forceinline__ int imax(int a, int b) { return a > b ? a : b; }
static __device__ __forceinline__ int imin(int a, int b) { return a < b ? a : b; }

__device__ __constant__ float LIFT_C[6] = {
  -0.5f, 0.25f,                                            // bior53
  -1.586134342f, -0.05298011854f, 0.8829110762f, 0.4435068522f  // bior97
};

// raw (unnormalized) FIR lowpass filters concatenated: db4(8) db6(12) sym6(12) coif5(30)
__device__ constexpr float FIRC[62] = {
  -0.0105974017850021f, 0.0328830116668852f, 0.0308413818355607f, -0.1870348117188811f,
  -0.0279837694169839f, 0.6308807679295904f, 0.7148465705529155f, 0.2303778133088964f,
  0.00107730108499558f, -0.00477725751101065f, -0.0005538422009938f, 0.03158203931748603f,
  0.02752286553030533f, -0.0975016055873225f, -0.12976686756709563f, 0.22626469396544f,
  0.3152503517092432f, -0.7511339080210959f, 0.4946238903984534f, 0.1115407433501095f,
  -0.007800708325034148f, 0.001767711864242804f, 0.04472490177066578f, -0.02106029251230056f,
  -0.0726375227866f, 0.3379294217282401f, 0.787641141030194f, 0.4910559419267466f,
  -0.048311742585632f, -0.1179901111484105f, 0.00349071208421747f, 0.01540410932702737f,
  -3.459977283621256e-05f, -7.098330313814114e-05f, 0.0004662169601128863f, 0.001117518770890601f,
  -0.002574517688750223f, -0.00900797613666158f, 0.015880544863615904f, 0.03455502757306163f,
  -0.08230192710688598f, -0.07179982161931202f, 0.42848347637761874f, 0.7937772226256206f,
  0.4051769024096169f, -0.06112339000267287f, -0.06577191128185562f, 0.023452696141836267f,
  0.007782596427325418f, -0.003793512864491014f, -0.0002606761356811993f, 0.000107502882505652f,
  1.10319778524429e-05f, -5.520763127949e-06f, -1.0682196848076e-06f, 5.236425333584e-07f,
  1.125098976034e-07f, -5.417490769329e-08f, -8.8631e-09f, 4.2921e-09f, 6.7e-10f, -3.2e-10f,
};

// ---------------- gate: 1x1 conv -> relu -> 1x1 conv -> softmax -> renorm ----------------
__global__ __launch_bounds__(256) void k_gate(
    const float* __restrict__ x, const float* __restrict__ w1, const float* __restrict__ b1,
    const float* __restrict__ w2, const float* __restrict__ b2, float* __restrict__ gate)
{
  __shared__ float w1s[256], b1s[8], w2s[48], b2s[6];
  int tid = threadIdx.x;
  w1s[tid] = w1[tid];
  if (tid < 8)  b1s[tid] = b1[tid];
  if (tid < 48) w2s[tid] = w2[tid];
  if (tid < 6)  b2s[tid] = b2[tid];
  __syncthreads();
  int px = blockIdx.x * 256 + tid;        // exactly 4*HW threads
  int b = px / HW, p = px - b * HW;
  const float* xb = x + (size_t)b * 32 * HW + p;
  float xv[32];
#pragma unroll
  for (int c = 0; c < 32; ++c) xv[c] = xb[(size_t)c * HW];
  float hb[8];
#pragma unroll
  for (int j = 0; j < 8; ++j) {
    float s = b1s[j];
#pragma unroll
    for (int c = 0; c < 32; ++c) s += w1s[j * 32 + c] * xv[c];
    hb[j] = fmaxf(s, 0.f);
  }
  float e[6], mx = -1e30f;
#pragma unroll
  for (int k = 0; k < 6; ++k) {
    float s = b2s[k];
#pragma unroll
    for (int j = 0; j < 8; ++j) s += w2s[k * 8 + j] * hb[j];
    e[k] = s; mx = fmaxf(mx, s);
  }
  float se = 0.f;
#pragma unroll
  for (int k = 0; k < 6; ++k) { e[k] = expf(e[k] - mx); se += e[k]; }
  float inv = 1.f / se, s2 = 0.f;
#pragma unroll
  for (int k = 0; k < 6; ++k) { e[k] *= inv; s2 += e[k]; }
  float inv2 = 1.f / (s2 + 1e-12f);
  float* gp = gate + (size_t)b * 6 * HW + p;
#pragma unroll
  for (int k = 0; k < 6; ++k) gp[(size_t)k * HW] = e[k] * inv2;
}

// ---------------- fused 2D lifting: whole image in LDS, in-place ----------------
// grid (128 imgs, 2 cands), 1024 threads, 148224 B dynamic LDS
__global__ __launch_bounds__(1024) void k_lift(
    const float* __restrict__ x, float* __restrict__ halfp,
    const float* __restrict__ s53A, const float* __restrict__ s53D,
    const float* __restrict__ s97A, const float* __restrict__ s97D)
{
  extern __shared__ float xs[];   // [192][193]
  const int tid = threadIdx.x;
  const int img = blockIdx.x;
  const int cand = blockIdx.y;    // 0: bior53, 1: bior97
  const float* xi = x + (size_t)img * HW;
  for (int i = tid; i < HW; i += 1024) {
    int r = i / 192, c = i - r * 192;
    xs[r * 193 + c] = xi[i];
  }
  __syncthreads();
  const int base = cand ? 2 : 0, ns = cand ? 4 : 2;
  for (int s = 0; s < ns; ++s) {
    const float cf = LIFT_C[base + s] * 0.5f;
    for (int i = tid; i < 192 * 96; i += 1024) {
      int j = i % 96, r = i / 96;
      int jm = (j == 0) ? 1 : j - 1, jp = (j == 95) ? 94 : j + 1;
      float* row = xs + r * 193;
      if ((s & 1) == 0) row[2 * j + 1] += cf * (row[2 * jm] + row[2 * jp]);
      else              row[2 * j]     += cf * (row[2 * jm + 1] + row[2 * jp + 1]);
    }
    __syncthreads();
  }
  for (int s = 0; s < ns; ++s) {
    const float cf = LIFT_C[base + s] * 0.5f;
    for (int i = tid; i < 192 * 96; i += 1024) {
      int c = i % 192, j = i / 192;
      int jm = (j == 0) ? 1 : j - 1, jp = (j == 95) ? 94 : j + 1;
      if ((s & 1) == 0) xs[(2 * j + 1) * 193 + c] += cf * (xs[(2 * jm) * 193 + c] + xs[(2 * jp) * 193 + c]);
      else              xs[(2 * j) * 193 + c]     += cf * (xs[(2 * jm + 1) * 193 + c] + xs[(2 * jp + 1) * 193 + c]);
    }
    __syncthreads();
  }
  const float sA = cand ? s97A[0] : s53A[0];
  const float sD = cand ? s97D[0] : s53D[0];
  const float sc[4] = { sA * sA, sA * sD, sA * sD, sD * sD };   // hf applied later at sf store
  for (int i = tid; i < 4 * 9216; i += 1024) {
    int s = i / 9216, p = i - s * 9216;
    int u = p / 96, v = p - u * 96;
    int ro = (s & 1) ? (2 * u + 1) : (2 * u);
    int co = (s & 2) ? (2 * v + 1) : (2 * v);
    halfp[((size_t)(cand * 4 + s) * IMGS + img) * 9216 + p] = sc[s] * xs[ro * 193 + co];
  }
}

// ---------------- W pass: each conv position computed exactly ONCE ----------------
// Block = 4 image rows. Phase A: 192 positions/row/cand into LDS (each once).
// Phase B: blend (W resize fused) and store fp16 plane rows. Removes the tile
// scheme's 2.27x redundant W compute (2x row halo x 9-for-8 positions).
template<int L, int PA, int OFF>
__device__ __forceinline__ void wpass_cand(
    const float* xs, float* posL, float* posH, int tid,
    __half* __restrict__ pl, __half* __restrict__ ph)
{
  const int row = tid >> 6, pc = tid & 63;
  const int xbase = row * 224 + pc + 15 - PA;
#pragma unroll
  for (int j = 0; j < 3; ++j) {
    float a = 0.f, d = 0.f;
    const int xb = xbase + 64 * j;
#pragma unroll
    for (int jj = 0; jj < L; ++jj) {
      const float v = xs[xb + jj];
      a += FIRC[OFF + jj] * v;
      d += (((jj & 1) ? -1.f : 1.f) * FIRC[OFF + L - 1 - jj]) * v;
    }
    posL[row * 192 + pc + 64 * j] = a;
    posH[row * 192 + pc + 64 * j] = d;
  }
  __syncthreads();
  const float* pr = posL + row * 192;
  const float* qr = posH + row * 192;
#pragma unroll
  for (int j = 0; j < 3; ++j) {
    const int w = pc + 64 * j;
    const int dd = (w >= 96) ? 2 : 1;
    const float t = (float)dd - (float)(2 * w + 1) * (1.f / 192.f);
    const int q0 = w - dd;
    const int i0 = imax(q0, 0);
    const int i1 = imin(q0 + 1, 189);
    const float v0 = pr[i0], v1 = pr[i1];
    pl[(size_t)row * 192 + w] = __float2half(fmaf(t, v1 - v0, v0));
    const float u0 = qr[i0], u1 = qr[i1];
    ph[(size_t)row * 192 + w] = __float2half(fmaf(t, u1 - u0, u0));
  }
  __syncthreads();
}

__global__ __launch_bounds__(256) void k_wpass(
    const float* __restrict__ x, __half* __restrict__ planes)
{
  __shared__ float xs[896];            // 4 rows x 224 (15-col reflect halo each side)
  __shared__ float posL[768], posH[768];
  const int tid = threadIdx.x;
  const int r0 = blockIdx.x * 4;
  const int img = blockIdx.y;
  const float* xi = x + (size_t)img * HW;
  for (int v = tid; v < 896; v += 256) {
    int rr = v / 224, scc = v - rr * 224 - 15;
    int sc = scc < 0 ? -scc : (scc > 191 ? 382 - scc : scc);
    xs[v] = xi[(size_t)(r0 + rr) * 192 + sc];
  }
  __syncthreads();
  const size_t ib = (size_t)img * HW + (size_t)r0 * 192;
  const size_t PS = (size_t)IMGS * HW;
  wpass_cand<8, 2, 0>(xs, posL, posH, tid, planes + ib, planes + PS + ib);
  wpass_cand<12, 4, 8>(xs, posL, posH, tid, planes + 2 * PS + ib, planes + 3 * PS + ib);
  wpass_cand<12, 4, 20>(xs, posL, posH, tid, planes + 4 * PS + ib, planes + 5 * PS + ib);
  wpass_cand<30, 13, 32>(xs, posL, posH, tid, planes + 6 * PS + ib, planes + 7 * PS + ib);
}

// ---------------- H pass for one candidate (32x32 tile) ----------------
// Stages fp16 L/H plane windows (64 rows incl. reflect halo) into padded LDS,
// then column conv + H-resize blend into gated accumulators. Branch-split
// (LL/LH consumed before HL/HH computed) to halve live conv state.
template<int L, int PA, int OFF, int CHH>
__device__ __forceinline__ void hpass_cand(
    const __half* __restrict__ pL, const __half* __restrict__ pH,
    float* lbs, float* hbs, int tid, int h0, int w0, int c,
    int rb0, float t0h, int topH, int botH,
    const float* __restrict__ gp, float (&acc)[4][4])
{
  float ss = 0.f;
#pragma unroll
  for (int j = 0; j < L; ++j) ss += FIRC[OFF + j] * FIRC[OFF + j];
  const float invn = 1.f / (sqrtf(ss) + 1e-12f);
  const float invn2 = invn * invn;

  for (int v = tid; v < 2048; v += 256) {
    int l = v >> 5, cc = v & 31;
    int prr = h0 - 16 + l; prr = prr < 0 ? -prr : (prr > 191 ? 382 - prr : prr);
    size_t off = (size_t)prr * 192 + (w0 + cc);
    lbs[l * 33 + cc] = __half2float(pL[off]);
    hbs[l * 33 + cc] = __half2float(pH[off]);
  }
  __syncthreads();
  const int rb = rb0 - PA;
  // branch 1: lbs -> LL/LH -> acc[.][0..1]
  {
    float Ap[5], Dp[5];
#pragma unroll
    for (int p = 0; p < 5; ++p) { Ap[p] = 0.f; Dp[p] = 0.f; }
#pragma unroll
    for (int c0 = 0; c0 < L; c0 += CHH) {
      const int CL = (c0 + CHH <= L) ? CHH : (L - c0);
      float win[CHH + 4];
#pragma unroll
      for (int m = 0; m < CL + 4; ++m) win[m] = lbs[(rb + c0 + m) * 33 + c];
#pragma unroll
      for (int p = 0; p < 5; ++p) {
        float a = Ap[p], d = Dp[p];
#pragma unroll
        for (int j = 0; j < CL; ++j) {
          const float v = win[p + j];
          a += FIRC[OFF + c0 + j] * v;
          d += ((((c0 + j) & 1) ? -1.f : 1.f) * FIRC[OFF + L - 1 - (c0 + j)]) * v;
        }
        Ap[p] = a; Dp[p] = d;
      }
    }
#pragma unroll
    for (int k = 0; k < 4; ++k) {
      const float t = t0h - (float)k * (1.f / 96.f);
      float v0a = Ap[k], v1a = Ap[k + 1];
      float v0b = Dp[k], v1b = Dp[k + 1];
      if (k == 0 && topH) { v0a = v1a = Ap[1]; v0b = v1b = Dp[1]; }
      if (k == 3 && botH) { v1a = v0a; v1b = v0b; }
      const float gv = gp[k * 192] * invn2;
      acc[k][0] += gv * fmaf(t, v1a - v0a, v0a);
      acc[k][1] += gv * fmaf(t, v1b - v0b, v0b);
    }
  }
  // branch 2: hbs -> HL/HH -> acc[.][2..3]
  {
    float Ap[5], Dp[5];
#pragma unroll
    for (int p = 0; p < 5; ++p) { Ap[p] = 0.f; Dp[p] = 0.f; }
#pragma unroll
    for (int c0 = 0; c0 < L; c0 += CHH) {
      const int CL = (c0 + CHH <= L) ? CHH : (L - c0);
      float win[CHH + 4];
#pragma unroll
      for (int m = 0; m < CL + 4; ++m) win[m] = hbs[(rb + c0 + m) * 33 + c];
#pragma unroll
      for (int p = 0; p < 5; ++p) {
        float a = Ap[p], d = Dp[p];
#pragma unroll
        for (int j = 0; j < CL; ++j) {
          const float v = win[p + j];
          a += FIRC[OFF + c0 + j] * v;
          d += ((((c0 + j) & 1) ? -1.f : 1.f) * FIRC[OFF + L - 1 - (c0 + j)]) * v;
        }
        Ap[p] = a; Dp[p] = d;
      }
    }
#pragma unroll
    for (int k = 0; k < 4; ++k) {
      const float t = t0h - (float)k * (1.f / 96.f);
      float v0a = Ap[k], v1a = Ap[k + 1];
      float v0b = Dp[k], v1b = Dp[k + 1];
      if (k == 0 && topH) { v0a = v1a = Ap[1]; v0b = v1b = Dp[1]; }
      if (k == 3 && botH) { v1a = v0a; v1b = v0b; }
      const float gv = gp[k * 192] * invn2;
      acc[k][2] += gv * fmaf(t, v1a - v0a, v0a);
      acc[k][3] += gv * fmaf(t, v1b - v0b, v0b);
    }
  }
  __syncthreads();
}

// ---------------- fused per-tile kernel: H pass x4 cands + lifting gather + gate ----------------
__global__ __launch_bounds__(256) void k_hfuse(
    const float* __restrict__ gate, const __half* __restrict__ planes,
    const float* __restrict__ halfp, const float* __restrict__ hfp, __half* __restrict__ sf)
{
  __shared__ float wb[2 * 64 * 33];
  float* lbs = wb;
  float* hbs = wb + 64 * 33;
  const int tid = threadIdx.x;
  const int tile = blockIdx.x;
  const int ty = tile / 6, tx = tile - ty * 6;
  const int img = blockIdx.y;
  const int b = img >> 5;
  const int h0 = ty * 32, w0 = tx * 32;
  const int c = tid & 31, g2 = tid >> 5;
  const int hfirst = h0 + g2 * 4;
  const int dH = (hfirst >= 96) ? 2 : 1;
  const float t0h = (float)dH - (float)(2 * hfirst + 1) * (1.f / 192.f);
  const int rb0 = g2 * 4 - dH + 16;
  const int topH = (hfirst == 0), botH = (hfirst == 188);
  const int wpx = w0 + c;
  const float* gbase = gate + (size_t)(b * 6) * HW + (size_t)hfirst * 192 + wpx;
  float acc[4][4];
#pragma unroll
  for (int k = 0; k < 4; ++k)
#pragma unroll
    for (int s = 0; s < 4; ++s) acc[k][s] = 0.f;

  const size_t pb = (size_t)img * HW;
  const size_t PS = (size_t)IMGS * HW;
  hpass_cand<8, 2, 0, 8>(planes + pb, planes + PS + pb, lbs, hbs, tid, h0, w0, c,
                         rb0, t0h, topH, botH, gbase, acc);
  hpass_cand<12, 4, 8, 12>(planes + 2 * PS + pb, planes + 3 * PS + pb, lbs, hbs, tid, h0, w0, c,
                           rb0, t0h, topH, botH, gbase + HW, acc);
  hpass_cand<12, 4, 20, 12>(planes + 4 * PS + pb, planes + 5 * PS + pb, lbs, hbs, tid, h0, w0, c,
                            rb0, t0h, topH, botH, gbase + 2 * HW, acc);
  hpass_cand<30, 13, 32, 15>(planes + 6 * PS + pb, planes + 7 * PS + pb, lbs, hbs, tid, h0, w0, c,
                             rb0, t0h, topH, botH, gbase + 3 * HW, acc);

  // ---- lifting gather: stage 18x18 half-res windows of 8 planes as [pos][4] ----
  float* ls4 = wb;   // reuse (2592 <= 4224 floats); safe: barrier at end of hpass_cand
  const int hu0 = (h0 >> 1) - 1, wv0 = (w0 >> 1) - 1;
  for (int v = tid; v < 2592; v += 256) {
    int lv = v % 18; int r1 = v / 18;
    int lu = r1 % 18; int ps = r1 / 18;      // ps = lc*4+s
    int lc = ps >> 2;
    int gu = imin(imax(hu0 + lu, 0), 95);
    int gv = imin(imax(wv0 + lv, 0), 95);
    ls4[(lc * 324 + lu * 18 + lv) * 4 + (ps & 3)] =
        halfp[((size_t)ps * IMGS + img) * 9216 + (size_t)gu * 96 + gv];
  }
  __syncthreads();

  const int v0c = (wpx >> 1) + (wpx & 1) - 1;
  const float tv = (wpx & 1) ? 0.25f : 0.75f;
  const int lv0 = imax(v0c, 0) - wv0;
  const int lv1 = imin(v0c + 1, 95) - wv0;
#pragma unroll
  for (int k = 0; k < 4; ++k) {
    const int h = hfirst + k;
    const int u0 = (h >> 1) + (h & 1) - 1;
    const float tu = (h & 1) ? 0.25f : 0.75f;
    const int lu0 = imax(u0, 0) - hu0;
    const int lu1 = imin(u0 + 1, 95) - hu0;
    const float w00 = (1.f - tu) * (1.f - tv), w01 = (1.f - tu) * tv;
    const float w10 = tu * (1.f - tv), w11 = tu * tv;
#pragma unroll
    for (int lc = 0; lc < 2; ++lc) {
      const int b00 = (lc * 324 + lu0 * 18 + lv0) * 4;
      const int b01 = (lc * 324 + lu0 * 18 + lv1) * 4;
      const int b10 = (lc * 324 + lu1 * 18 + lv0) * 4;
      const int b11 = (lc * 324 + lu1 * 18 + lv1) * 4;
      const float gv = gbase[(size_t)(4 + lc) * HW + k * 192];
#pragma unroll
      for (int s = 0; s < 4; ++s) {
        float val = w00 * ls4[b00 + s] + w01 * ls4[b01 + s] +
                    w10 * ls4[b10 + s] + w11 * ls4[b11 + s];
        acc[k][s] += gv * val;
      }
    }
  }
  // ---- store Sf as fp16 (hf folded in here, once, for all candidates) ----
  const float hfv = hfp[0];
#pragma unroll
  for (int k = 0; k < 4; ++k) {
    const int h = hfirst + k;
    size_t basep = (size_t)img * 4 * HW + (size_t)h * 192 + wpx;
    sf[basep]          = __float2half(acc[k][0]);
    sf[basep + HW]     = __float2half(hfv * acc[k][1]);
    sf[basep + 2 * HW] = __float2half(hfv * acc[k][2]);
    sf[basep + 3 * HW] = __float2half(hfv * acc[k][3]);
  }
}

// ---------------- final 1x1 projection 128 -> 32 ----------------
// 2304 blocks x 256 thr; 4 waves/block share one 64-px slab (L1 reuse);
// weights via wave-uniform (readfirstlane) scalar loads.
__global__ __launch_bounds__(256) void k_proj(
    const __half* __restrict__ sf, const float* __restrict__ pw,
    const float* __restrict__ pb, float* __restrict__ out)
{
  const int tid = threadIdx.x;
  const int lane = tid & 63;
  const int og = __builtin_amdgcn_readfirstlane(tid >> 6);   // 0..3, wave-uniform scalar
  const int b = blockIdx.x / 576;                             // 576 blocks per image
  const int p = blockIdx.x * 64 - b * HW + lane;
  const __half* sfb = sf + (size_t)(b * 128) * HW + p;
  const float* pwb = pw + og * 8 * 128;                       // scalar base
  float acc[8];
#pragma unroll
  for (int oo = 0; oo < 8; ++oo) acc[oo] = 0.f;
#pragma unroll 4
  for (int ch = 0; ch < 128; ++ch) {
    const float v = __half2float(sfb[(size_t)ch * HW]);
#pragma unroll
    for (int oo = 0; oo < 8; ++oo) acc[oo] = fmaf(pwb[oo * 128 + ch], v, acc[oo]);
  }
#pragma unroll
  for (int oo = 0; oo < 8; ++oo) {
    out[(size_t)(b * 32 + og * 8 + oo) * HW + p] = acc[oo] + pb[og * 8 + oo];
  }
}

extern "C" void kernel_launch(void* const* d_in, const int* in_sizes, int n_in,
                              void* d_out, int out_size, void* d_ws, size_t ws_size,
                              hipStream_t stream) {
  (void)in_sizes; (void)n_in; (void)out_size; (void)ws_size;
  const float* x    = (const float*)d_in[0];
  const float* gw1  = (const float*)d_in[1];
  const float* gb1  = (const float*)d_in[2];
  const float* gw2  = (const float*)d_in[3];
  const float* gb2  = (const float*)d_in[4];
  const float* s53A = (const float*)d_in[5];
  const float* s53D = (const float*)d_in[6];
  const float* s97A = (const float*)d_in[7];
  const float* s97D = (const float*)d_in[8];
  const float* hfp  = (const float*)d_in[9];
  const float* pw   = (const float*)d_in[10];
  const float* pb   = (const float*)d_in[11];
  float* out = (float*)d_out;

  // workspace layout (bytes):
  //   gate   fp32:          0 ..  3,538,944
  //   half   fp32:  3,538,944 .. 41,287,680
  //   planes fp16: 41,287,680 .. 116,785,152   (8 x 128 x 192 x 192)
  //   sf     fp16: 116,785,152 .. 154,533,888
  float*  gate   = (float*)d_ws;
  float*  halfp  = (float*)((char*)d_ws + 3538944);
  __half* planes = (__half*)((char*)d_ws + 41287680);
  __half* sf     = (__half*)((char*)d_ws + 116785152);

  hipLaunchKernelGGL(k_gate, dim3(576), dim3(256), 0, stream, x, gw1, gb1, gw2, gb2, gate);
  hipLaunchKernelGGL(k_lift, dim3(128, 2), dim3(1024), 192 * 193 * 4, stream,
                     x, halfp, s53A, s53D, s97A, s97D);
  hipLaunchKernelGGL(k_wpass, dim3(48, 128), dim3(256), 0, stream, x, planes);
  hipLaunchKernelGGL(k_hfuse, dim3(36, 128), dim3(256), 0, stream, gate, planes, halfp, hfp, sf);
  hipLaunchKernelGGL(k_proj, dim3(2304), dim3(256), 0, stream, sf, pw, pb, out);
}